// Round 18
// baseline (112.129 us; speedup 1.0000x reference)
//
#include <hip/hip_runtime.h>

#define TDIM 4096
#define BDIM 256
#define ADIM 26
#define SDIM 4
#define NEGF -1e30f
#define LOG2E 1.44269504088896340736f

__device__ __forceinline__ float ex2(float x) { return __builtin_amdgcn_exp2f(x); }
__device__ __forceinline__ float lg2(float x) { return __builtin_amdgcn_logf(x); }

__device__ __forceinline__ float l2se2(float a, float b) {
    float mx = fmaxf(a, b), mn = fminf(a, b);
    return mx + lg2(1.f + ex2(mn - mx));
}
__device__ __forceinline__ float l2se3(float a, float b, float c) {
    float mx = fmaxf(fmaxf(a, b), c);
    float md = __builtin_amdgcn_fmed3f(a, b, c);
    float mn = fminf(fminf(a, b), c);
    return mx + lg2(1.f + ex2(md - mx) + ex2(mn - mx));
}
__device__ __forceinline__ float l2se4(float a, float b, float c, float d) {
    float h1 = fmaxf(a, b), l1 = fminf(a, b);
    float h2 = fmaxf(c, d), l2 = fminf(c, d);
    float mx = fmaxf(h1, h2), s2 = fminf(h1, h2);
    return mx + lg2(1.f + ex2(s2 - mx) + ex2(l1 - mx) + ex2(l2 - mx));
}

struct TransA { float A00, A01, A02, A11, A12, A13, A22, A23, A33; };

__device__ __forceinline__ TransA make_transA(const float* __restrict__ trans) {
    TransA A;
    {
        float l0 = trans[0], l1 = trans[1], l2 = trans[2];
        float m = fmaxf(fmaxf(l0, l1), l2);
        float lz = m + __logf(__expf(l0 - m) + __expf(l1 - m) + __expf(l2 - m));
        A.A00 = (l0 - lz) * LOG2E; A.A01 = (l1 - lz) * LOG2E; A.A02 = (l2 - lz) * LOG2E;
    }
    {
        float l1 = trans[5], l2 = trans[6], l3 = trans[7];
        float m = fmaxf(fmaxf(l1, l2), l3);
        float lz = m + __logf(__expf(l1 - m) + __expf(l2 - m) + __expf(l3 - m));
        A.A11 = (l1 - lz) * LOG2E; A.A12 = (l2 - lz) * LOG2E; A.A13 = (l3 - lz) * LOG2E;
    }
    {
        float l2 = trans[10], l3 = trans[11];
        float m = fmaxf(l2, l3);
        float lz = m + __logf(__expf(l2 - m) + __expf(l3 - m));
        A.A22 = (l2 - lz) * LOG2E; A.A23 = (l3 - lz) * LOG2E;
    }
    A.A33 = 0.f;
    return A;
}

struct UT { float m00, m01, m02, m03, m11, m12, m13, m22, m23, m33; };

__device__ __forceinline__ void fstep(UT& M, const TransA& A, float4 e) {
    float n00 = M.m00 + A.A00 + e.x;
    float n01 = l2se2(M.m00 + A.A01, M.m01 + A.A11) + e.y;
    float n02 = l2se3(M.m00 + A.A02, M.m01 + A.A12, M.m02 + A.A22) + e.z;
    float n03 = l2se3(M.m01 + A.A13, M.m02 + A.A23, M.m03) + e.w;
    float n11 = M.m11 + A.A11 + e.y;
    float n12 = l2se2(M.m11 + A.A12, M.m12 + A.A22) + e.z;
    float n13 = l2se3(M.m11 + A.A13, M.m12 + A.A23, M.m13) + e.w;
    float n22 = M.m22 + A.A22 + e.z;
    float n23 = l2se2(M.m22 + A.A23, M.m23) + e.w;
    float n33 = M.m33 + e.w;
    M.m00 = n00; M.m01 = n01; M.m02 = n02; M.m03 = n03;
    M.m11 = n11; M.m12 = n12; M.m13 = n13; M.m22 = n22; M.m23 = n23; M.m33 = n33;
}

__device__ __forceinline__ UT ut_compose(const UT& A, const UT& B) {
    UT C;
    C.m00 = A.m00 + B.m00;
    C.m01 = l2se2(A.m00 + B.m01, A.m01 + B.m11);
    C.m02 = l2se3(A.m00 + B.m02, A.m01 + B.m12, A.m02 + B.m22);
    C.m03 = l2se4(A.m00 + B.m03, A.m01 + B.m13, A.m02 + B.m23, A.m03 + B.m33);
    C.m11 = A.m11 + B.m11;
    C.m12 = l2se2(A.m11 + B.m12, A.m12 + B.m22);
    C.m13 = l2se3(A.m11 + B.m13, A.m12 + B.m23, A.m13 + B.m33);
    C.m22 = A.m22 + B.m22;
    C.m23 = l2se2(A.m22 + B.m23, A.m23 + B.m33);
    C.m33 = A.m33 + B.m33;
    return C;
}

__device__ __forceinline__ void ut_renorm(UT& M) {
    float m1 = fmaxf(fmaxf(M.m00, M.m01), fmaxf(M.m02, M.m03));
    float m2 = fmaxf(fmaxf(M.m11, M.m12), fmaxf(M.m13, M.m22));
    float m3 = fmaxf(M.m23, M.m33);
    float mx = fmaxf(fmaxf(m1, m2), m3);
    M.m00 -= mx; M.m01 -= mx; M.m02 -= mx; M.m03 -= mx;
    M.m11 -= mx; M.m12 -= mx; M.m13 -= mx; M.m22 -= mx; M.m23 -= mx; M.m33 -= mx;
}

__device__ __forceinline__ void ut_store11(float* p, const UT& M) {
    p[0] = M.m00; p[1] = M.m01; p[2] = M.m02; p[3] = M.m03;
    p[4] = M.m11; p[5] = M.m12; p[6] = M.m13;
    p[7] = M.m22; p[8] = M.m23; p[9] = M.m33;
}
__device__ __forceinline__ UT ut_load11(const float* p) {
    UT M;
    M.m00 = p[0]; M.m01 = p[1]; M.m02 = p[2]; M.m03 = p[3];
    M.m11 = p[4]; M.m12 = p[5]; M.m13 = p[6];
    M.m22 = p[7]; M.m23 = p[8]; M.m33 = p[9];
    return M;
}

// v' = v (x) M  (row-vec), renormed
__device__ __forceinline__ void vecmat(float& v0, float& v1, float& v2, float& v3,
                                       const float* m) {
    float n0 = v0 + m[0];
    float n1 = l2se2(v0 + m[1], v1 + m[4]);
    float n2 = l2se3(v0 + m[2], v1 + m[5], v2 + m[7]);
    float n3 = l2se4(v0 + m[3], v1 + m[6], v2 + m[8], v3 + m[9]);
    float mm = fmaxf(fmaxf(n0, n1), fmaxf(n2, n3));
    v0 = n0 - mm; v1 = n1 - mm; v2 = n2 - mm; v3 = n3 - mm;
}
// u' = M (x) u  (col-vec), renormed
__device__ __forceinline__ void matvec(const float* m,
                                       float& u0, float& u1, float& u2, float& u3) {
    float n0 = l2se4(m[0] + u0, m[1] + u1, m[2] + u2, m[3] + u3);
    float n1 = l2se3(m[4] + u1, m[5] + u2, m[6] + u3);
    float n2 = l2se2(m[7] + u2, m[8] + u3);
    float n3 = m[9] + u3;
    float mm = fmaxf(fmaxf(n0, n1), fmaxf(n2, n3));
    u0 = n0 - mm; u1 = n1 - mm; u2 = n2 - mm; u3 = n3 - mm;
}

#define ASTEP(E) do { \
    float4 _e = (E); \
    float n0_ = a0 + A.A00; \
    float n1_ = l2se2(a0 + A.A01, a1 + A.A11); \
    float n2_ = l2se3(a0 + A.A02, a1 + A.A12, a2 + A.A22); \
    float n3_ = l2se3(a1 + A.A13, a2 + A.A23, a3); \
    a0 = n0_ + _e.x; a1 = n1_ + _e.y; a2 = n2_ + _e.z; a3 = n3_ + _e.w; \
    float mm_ = fmaxf(fmaxf(a0, a1), fmaxf(a2, a3)); \
    a0 -= mm_; a1 -= mm_; a2 -= mm_; a3 -= mm_; \
} while (0)

#define BSTEP(E) do { \
    float4 _e = (E); \
    float f0_ = _e.x + b0, f1_ = _e.y + b1, f2_ = _e.z + b2, f3_ = _e.w + b3; \
    float n0_ = l2se3(A.A00 + f0_, A.A01 + f1_, A.A02 + f2_); \
    float n1_ = l2se3(A.A11 + f1_, A.A12 + f2_, A.A13 + f3_); \
    float n2_ = l2se2(A.A22 + f2_, A.A23 + f3_); \
    float n3_ = f3_; \
    float bm_ = fmaxf(fmaxf(n0_, n1_), fmaxf(n2_, n3_)); \
    b0 = n0_ - bm_; b1 = n1_ - bm_; b2 = n2_ - bm_; b3 = n3_ - bm_; \
} while (0)

#define GEMIT(AV, Q) do { \
    float g0_ = (AV).x + b0, g1_ = (AV).y + b1, g2_ = (AV).z + b2, g3_ = (AV).w + b3; \
    float gm_ = fmaxf(fmaxf(g0_, g1_), fmaxf(g2_, g3_)); \
    float q0_ = ex2(g0_ - gm_), q1_ = ex2(g1_ - gm_); \
    float q2_ = ex2(g2_ - gm_), q3_ = ex2(g3_ - gm_); \
    float inv_ = 1.f / (q0_ + q1_ + q2_ + q3_); \
    q0_ *= inv_; q1_ *= inv_; q2_ *= inv_; q3_ *= inv_; \
    vals[(Q)*5 + 0] = fmaf(q0_, wv[0][0], fmaf(q1_, wv[1][0], fmaf(q2_, wv[2][0], q3_ * wv[3][0]))); \
    vals[(Q)*5 + 1] = fmaf(q0_, wv[0][1], fmaf(q1_, wv[1][1], fmaf(q2_, wv[2][1], q3_ * wv[3][1]))); \
    vals[(Q)*5 + 2] = fmaf(q0_, wv[0][2], fmaf(q1_, wv[1][2], fmaf(q2_, wv[2][2], q3_ * wv[3][2]))); \
    vals[(Q)*5 + 3] = fmaf(q0_, wv[0][3], fmaf(q1_, wv[1][3], fmaf(q2_, wv[2][3], q3_ * wv[3][3]))); \
    vals[(Q)*5 + 4] = fmaf(q0_, wv[0][4], fmaf(q1_, wv[1][4], fmaf(q2_, wv[2][4], q3_ * wv[3][4]))); \
} while (0)

// le in LDS: row = t&7 (stride 513 float4), col = t>>3 = chunk id (C=512, L=8)
#define RDLE(T) sle[(((T) & 7) * 513) + ((T) >> 3)]

// op-tree float offsets in uni (stride 11 per op)
#define L0F 0
#define L0B 5632
#define L1F 11264
#define L1B 14080
#define L2F 16896
#define L2B 18304
#define L3F 19712
#define L3B 20416
#define L4F 21120
#define L4B 21472
#define SF  21824
#define SB  21952

__global__ __launch_bounds__(1024, 1)
void fused_kernel(const float* __restrict__ x, const float* __restrict__ emit,
                  const float* __restrict__ trans, const float* __restrict__ initl,
                  const float* __restrict__ w, float* __restrict__ out) {
    __shared__ float4 sle[8 * 513];     // 65,664 B
    __shared__ float4 uni[5520];        // 88,320 B: op tree (ph1/2) aliased by alpha/beta (ph3)
    __shared__ float Bmat[SDIM][ADIM];  // 416 B

    float* U = reinterpret_cast<float*>(uni);
    float4* abuf = uni;                 // [k*512 + c], k<4 (phase 3)
    float4* bbuf = uni + 2048;

    const int tid = threadIdx.x;
    const int bidb = blockIdx.x;

    // ---- emission distributions ----
    if (tid < SDIM) {
        float m = -1e30f;
        #pragma unroll
        for (int a = 0; a < ADIM; ++a) m = fmaxf(m, emit[tid * ADIM + a]);
        float tmp[ADIM];
        float z = 0.f;
        #pragma unroll
        for (int a = 0; a < ADIM; ++a) {
            float e = __expf(emit[tid * ADIM + a] - m);
            tmp[a] = e; z += e;
        }
        float inv = 1.f / z;
        #pragma unroll
        for (int a = 0; a < ADIM; ++a) Bmat[tid][a] = tmp[a] * inv;
    }
    TransA A = make_transA(trans);
    __syncthreads();

    // ---- phase 0: x -> le in LDS (rolled; 2 pairs/thread at 1024 threads) ----
    {
        const float4* xbase = reinterpret_cast<const float4*>(x) + (size_t)bidb * 2048 * 13;
        #pragma unroll 1
        for (int i = 0; i < 2; ++i) {
            const float4* xp = xbase + ((size_t)(i * 1024 + tid)) * 13;
            float4 buf[13];
            #pragma unroll
            for (int q = 0; q < 13; ++q) buf[q] = xp[q];

            float d00 = 0.f, d01 = 0.f, d02 = 0.f, d03 = 0.f;
            float d10 = 0.f, d11 = 0.f, d12 = 0.f, d13 = 0.f;
            #pragma unroll
            for (int q = 0; q < 13; ++q) {
                float4 u = buf[q];
                #pragma unroll
                for (int j = 0; j < 4; ++j) {
                    const int e = q * 4 + j;
                    float val = (j == 0) ? u.x : (j == 1) ? u.y : (j == 2) ? u.z : u.w;
                    float ev = ex2(val * LOG2E);
                    if (e < ADIM) {
                        d00 = fmaf(ev, Bmat[0][e], d00); d01 = fmaf(ev, Bmat[1][e], d01);
                        d02 = fmaf(ev, Bmat[2][e], d02); d03 = fmaf(ev, Bmat[3][e], d03);
                    } else {
                        const int a = e - ADIM;
                        d10 = fmaf(ev, Bmat[0][a], d10); d11 = fmaf(ev, Bmat[1][a], d11);
                        d12 = fmaf(ev, Bmat[2][a], d12); d13 = fmaf(ev, Bmat[3][a], d13);
                    }
                }
            }
            float4 r0, r1;
            r0.x = lg2(d00); r0.y = lg2(d01); r0.z = lg2(d02); r0.w = lg2(d03);
            r1.x = lg2(d10); r1.y = lg2(d11); r1.z = lg2(d12); r1.w = lg2(d13);
            int t = (i * 1024 + tid) << 1;
            RDLE(t) = r0;
            RDLE(t + 1) = r1;
        }
    }
    __syncthreads();

    const int c = tid & 511;
    const int t0 = c * 8;
    const bool isB = tid >= 512;

    // ---- phase 1: per-(chunk,dir) operator (L=8), rolled ----
    {
        UT M;
        if (!isB) {
            float4 e0 = RDLE(t0);
            if (c == 0) {
                M.m00 = e0.x; M.m11 = e0.y; M.m22 = e0.z; M.m33 = e0.w;
                M.m01 = NEGF; M.m02 = NEGF; M.m03 = NEGF; M.m12 = NEGF; M.m13 = NEGF; M.m23 = NEGF;
            } else {
                M.m00 = A.A00 + e0.x; M.m01 = A.A01 + e0.y; M.m02 = A.A02 + e0.z; M.m03 = NEGF;
                M.m11 = A.A11 + e0.y; M.m12 = A.A12 + e0.z; M.m13 = A.A13 + e0.w;
                M.m22 = A.A22 + e0.z; M.m23 = A.A23 + e0.w; M.m33 = e0.w;
            }
            #pragma unroll 1
            for (int k = 1; k < 8; ++k) fstep(M, A, RDLE(t0 + k));
            ut_renorm(M);
            ut_store11(U + L0F + c * 11, M);
        } else {
            M.m00 = 0.f; M.m11 = 0.f; M.m22 = 0.f; M.m33 = 0.f;
            M.m01 = NEGF; M.m02 = NEGF; M.m03 = NEGF; M.m12 = NEGF; M.m13 = NEGF; M.m23 = NEGF;
            int nst = (c == 511) ? 7 : 8;
            #pragma unroll 1
            for (int k = 0; k < nst; ++k) fstep(M, A, RDLE(t0 + 1 + k));
            ut_renorm(M);
            ut_store11(U + L0B + c * 11, M);
        }
    }
    __syncthreads();

    // ---- phase 2a: L0 pairs -> L1 (256/dir) ----
    if (tid < 512) {
        int dir = tid >> 8, i = tid & 255;
        const float* src = U + (dir ? L0B : L0F);
        float* dst = U + (dir ? L1B : L1F);
        UT P = ut_compose(ut_load11(src + (2 * i) * 11), ut_load11(src + (2 * i + 1) * 11));
        ut_renorm(P);
        ut_store11(dst + i * 11, P);
    }
    __syncthreads();

    // ---- phase 2b: L1 pairs -> L2 (128/dir) ----
    if (tid < 256) {
        int dir = tid >> 7, i = tid & 127;
        const float* src = U + (dir ? L1B : L1F);
        float* dst = U + (dir ? L2B : L2F);
        UT P = ut_compose(ut_load11(src + (2 * i) * 11), ut_load11(src + (2 * i + 1) * 11));
        ut_renorm(P);
        ut_store11(dst + i * 11, P);
    }
    __syncthreads();

    // ---- phase 2c: L2 pairs -> L3 (64/dir) ----
    if (tid < 128) {
        int dir = tid >> 6, i = tid & 63;
        const float* src = U + (dir ? L2B : L2F);
        float* dst = U + (dir ? L3B : L3F);
        UT P = ut_compose(ut_load11(src + (2 * i) * 11), ut_load11(src + (2 * i + 1) * 11));
        ut_renorm(P);
        ut_store11(dst + i * 11, P);
    }
    __syncthreads();

    // ---- phase 2d: L3 pairs -> L4 (32/dir) ----
    if (tid < 64) {
        int dir = tid >> 5, i = tid & 31;
        const float* src = U + (dir ? L3B : L3F);
        float* dst = U + (dir ? L4B : L4F);
        UT P = ut_compose(ut_load11(src + (2 * i) * 11), ut_load11(src + (2 * i + 1) * 11));
        ut_renorm(P);
        ut_store11(dst + i * 11, P);
    }
    __syncthreads();

    // ---- phase 2e: two scalar serial scans over 32 L4-ops (rolled) ----
    if (tid == 0) {
        float i0 = initl[0], i1 = initl[1], i2 = initl[2], i3 = initl[3];
        float m = fmaxf(fmaxf(i0, i1), fmaxf(i2, i3));
        float lz = m + __logf(__expf(i0 - m) + __expf(i1 - m) + __expf(i2 - m) + __expf(i3 - m));
        float v0 = (i0 - lz) * LOG2E, v1 = (i1 - lz) * LOG2E;
        float v2 = (i2 - lz) * LOG2E, v3 = (i3 - lz) * LOG2E;
        #pragma unroll 1
        for (int g = 0; g < 32; ++g) {
            U[SF + g * 4 + 0] = v0; U[SF + g * 4 + 1] = v1;
            U[SF + g * 4 + 2] = v2; U[SF + g * 4 + 3] = v3;
            vecmat(v0, v1, v2, v3, U + L4F + g * 11);
        }
    } else if (tid == 64) {
        float u0 = 0.f, u1 = 0.f, u2 = 0.f, u3 = 0.f;
        #pragma unroll 1
        for (int g = 31; g >= 0; --g) {
            U[SB + g * 4 + 0] = u0; U[SB + g * 4 + 1] = u1;
            U[SB + g * 4 + 2] = u2; U[SB + g * 4 + 3] = u3;
            matvec(U + L4B + g * 11, u0, u1, u2, u3);
        }
    }
    __syncthreads();

    // ---- phase 2f: downsweep to per-chunk boundaries (registers) ----
    float fa0, fa1, fa2, fa3;
    float fb0, fb1, fb2, fb3;
    {
        int g = c >> 4;
        if (!isB) {
            fa0 = U[SF + g * 4 + 0]; fa1 = U[SF + g * 4 + 1];
            fa2 = U[SF + g * 4 + 2]; fa3 = U[SF + g * 4 + 3];
            if (c & 8) vecmat(fa0, fa1, fa2, fa3, U + L3F + (2 * g) * 11);
            if (c & 4) vecmat(fa0, fa1, fa2, fa3, U + L2F + ((c >> 3) * 2) * 11);
            if (c & 2) vecmat(fa0, fa1, fa2, fa3, U + L1F + ((c >> 2) * 2) * 11);
            if (c & 1) vecmat(fa0, fa1, fa2, fa3, U + L0F + (c - 1) * 11);
        } else {
            fb0 = U[SB + g * 4 + 0]; fb1 = U[SB + g * 4 + 1];
            fb2 = U[SB + g * 4 + 2]; fb3 = U[SB + g * 4 + 3];
            if (!(c & 8)) matvec(U + L3B + (2 * g + 1) * 11, fb0, fb1, fb2, fb3);
            if (!(c & 4)) matvec(U + L2B + ((c >> 3) * 2 + 1) * 11, fb0, fb1, fb2, fb3);
            if (!(c & 2)) matvec(U + L1B + ((c >> 2) * 2 + 1) * 11, fb0, fb1, fb2, fb3);
            if (!(c & 1)) matvec(U + L0B + (c + 1) * 11, fb0, fb1, fb2, fb3);
        }
    }
    __syncthreads();   // op-tree reads done; abuf/bbuf may now clobber uni

    // ---- phase 3: replay + gamma.w emit ----
    float wv[SDIM][5];
    #pragma unroll
    for (int s = 0; s < SDIM; ++s)
        #pragma unroll
        for (int o = 0; o < 5; ++o) wv[s][o] = w[s * 5 + o];

    float* opb = out + (size_t)bidb * TDIM * 5;
    float vals[20];

    if (!isB) {
        float a0 = fa0, a1 = fa1, a2 = fa2, a3 = fa3;
        if (c == 0) {
            float4 e = RDLE(0);
            a0 += e.x; a1 += e.y; a2 += e.z; a3 += e.w;
            float mm = fmaxf(fmaxf(a0, a1), fmaxf(a2, a3));
            a0 -= mm; a1 -= mm; a2 -= mm; a3 -= mm;
        } else {
            ASTEP(RDLE(t0));
        }
        abuf[0 * 512 + c] = make_float4(a0, a1, a2, a3);
        #pragma unroll 1
        for (int k = 1; k < 4; ++k) {
            ASTEP(RDLE(t0 + k));
            abuf[k * 512 + c] = make_float4(a0, a1, a2, a3);
        }
        __syncthreads();
        float b0, b1, b2, b3;
        #pragma unroll
        for (int q = 0; q < 4; ++q) {
            int k = 4 + q;
            ASTEP(RDLE(t0 + k));
            float4 bv = bbuf[q * 512 + c];
            b0 = bv.x; b1 = bv.y; b2 = bv.z; b3 = bv.w;
            float4 av = make_float4(a0, a1, a2, a3);
            GEMIT(av, q);
        }
        float4* vo = reinterpret_cast<float4*>(opb + (size_t)(t0 + 4) * 5);
        vo[0] = make_float4(vals[0],  vals[1],  vals[2],  vals[3]);
        vo[1] = make_float4(vals[4],  vals[5],  vals[6],  vals[7]);
        vo[2] = make_float4(vals[8],  vals[9],  vals[10], vals[11]);
        vo[3] = make_float4(vals[12], vals[13], vals[14], vals[15]);
        vo[4] = make_float4(vals[16], vals[17], vals[18], vals[19]);
    } else {
        float b0 = fb0, b1 = fb1, b2 = fb2, b3 = fb3;
        bool lastc = (c == 511);
        #pragma unroll 1
        for (int k = 7; k >= 4; --k) {
            if (!(lastc && k == 7)) BSTEP(RDLE(t0 + 1 + k));
            bbuf[(k - 4) * 512 + c] = make_float4(b0, b1, b2, b3);
        }
        __syncthreads();
        #pragma unroll
        for (int q = 3; q >= 0; --q) {
            BSTEP(RDLE(t0 + 1 + q));
            float4 av = abuf[q * 512 + c];
            GEMIT(av, q);
        }
        float4* vo = reinterpret_cast<float4*>(opb + (size_t)t0 * 5);
        vo[0] = make_float4(vals[0],  vals[1],  vals[2],  vals[3]);
        vo[1] = make_float4(vals[4],  vals[5],  vals[6],  vals[7]);
        vo[2] = make_float4(vals[8],  vals[9],  vals[10], vals[11]);
        vo[3] = make_float4(vals[12], vals[13], vals[14], vals[15]);
        vo[4] = make_float4(vals[16], vals[17], vals[18], vals[19]);
    }
}

extern "C" void kernel_launch(void* const* d_in, const int* in_sizes, int n_in,
                              void* d_out, int out_size, void* d_ws, size_t ws_size,
                              hipStream_t stream) {
    const float* x     = (const float*)d_in[0];
    const float* emit  = (const float*)d_in[1];
    const float* trans = (const float*)d_in[2];
    const float* initl = (const float*)d_in[3];
    const float* w     = (const float*)d_in[4];
    float* out = (float*)d_out;

    hipLaunchKernelGGL(fused_kernel, dim3(BDIM), dim3(1024), 0, stream,
                       x, emit, trans, initl, w, out);
}

// Round 19
// 40.385 us; speedup vs baseline: 2.7765x; 2.7765x over previous
//
#include <hip/hip_runtime.h>

#define TDIM 4096
#define BDIM 256
#define ADIM 26
#define SDIM 4
#define LOG2E 1.44269504088896340736f

__device__ __forceinline__ float ex2(float x) { return __builtin_amdgcn_exp2f(x); }
__device__ __forceinline__ float rcp(float x) { return __builtin_amdgcn_rcpf(x); }

// Linear-probability transition matrix (masked row softmax), A33 = 1.
struct TransA { float A00, A01, A02, A11, A12, A13, A22, A23, A33; };

__device__ __forceinline__ TransA make_transA(const float* __restrict__ trans) {
    TransA A;
    {
        float l0 = trans[0], l1 = trans[1], l2 = trans[2];
        float m = fmaxf(fmaxf(l0, l1), l2);
        float e0 = __expf(l0 - m), e1 = __expf(l1 - m), e2 = __expf(l2 - m);
        float s = 1.f / (e0 + e1 + e2);
        A.A00 = e0 * s; A.A01 = e1 * s; A.A02 = e2 * s;
    }
    {
        float l1 = trans[5], l2 = trans[6], l3 = trans[7];
        float m = fmaxf(fmaxf(l1, l2), l3);
        float e1 = __expf(l1 - m), e2 = __expf(l2 - m), e3 = __expf(l3 - m);
        float s = 1.f / (e1 + e2 + e3);
        A.A11 = e1 * s; A.A12 = e2 * s; A.A13 = e3 * s;
    }
    {
        float l2 = trans[10], l3 = trans[11];
        float m = fmaxf(l2, l3);
        float e2 = __expf(l2 - m), e3 = __expf(l3 - m);
        float s = 1.f / (e2 + e3);
        A.A22 = e2 * s; A.A23 = e3 * s;
    }
    A.A33 = 1.f;
    return A;
}

// Upper-triangular linear operator, 10 entries. All scaling cancels in gamma.
struct UT { float m00, m01, m02, m03, m11, m12, m13, m22, m23, m33; };

// M <- rescale( M . (A * diag(e)) )
__device__ __forceinline__ void fstep(UT& M, const TransA& A, float4 e) {
    float n00 = M.m00 * A.A00 * e.x;
    float n01 = fmaf(M.m00, A.A01, M.m01 * A.A11) * e.y;
    float n02 = fmaf(M.m00, A.A02, fmaf(M.m01, A.A12, M.m02 * A.A22)) * e.z;
    float n03 = fmaf(M.m01, A.A13, fmaf(M.m02, A.A23, M.m03)) * e.w;   // A33=1
    float n11 = M.m11 * A.A11 * e.y;
    float n12 = fmaf(M.m11, A.A12, M.m12 * A.A22) * e.z;
    float n13 = fmaf(M.m11, A.A13, fmaf(M.m12, A.A23, M.m13)) * e.w;
    float n22 = M.m22 * A.A22 * e.z;
    float n23 = fmaf(M.m22, A.A23, M.m23) * e.w;
    float n33 = M.m33 * e.w;
    float m1 = fmaxf(fmaxf(n00, n01), fmaxf(n02, n03));
    float m2 = fmaxf(fmaxf(n11, n12), fmaxf(n13, n22));
    float s = rcp(fmaxf(fmaxf(m1, m2), fmaxf(n23, n33)));
    M.m00 = n00 * s; M.m01 = n01 * s; M.m02 = n02 * s; M.m03 = n03 * s;
    M.m11 = n11 * s; M.m12 = n12 * s; M.m13 = n13 * s;
    M.m22 = n22 * s; M.m23 = n23 * s; M.m33 = n33 * s;
}

// C = A . B (linear UT matmul)
__device__ __forceinline__ UT ut_compose(const UT& A, const UT& B) {
    UT C;
    C.m00 = A.m00 * B.m00;
    C.m01 = fmaf(A.m00, B.m01, A.m01 * B.m11);
    C.m02 = fmaf(A.m00, B.m02, fmaf(A.m01, B.m12, A.m02 * B.m22));
    C.m03 = fmaf(A.m00, B.m03, fmaf(A.m01, B.m13, fmaf(A.m02, B.m23, A.m03 * B.m33)));
    C.m11 = A.m11 * B.m11;
    C.m12 = fmaf(A.m11, B.m12, A.m12 * B.m22);
    C.m13 = fmaf(A.m11, B.m13, fmaf(A.m12, B.m23, A.m13 * B.m33));
    C.m22 = A.m22 * B.m22;
    C.m23 = fmaf(A.m22, B.m23, A.m23 * B.m33);
    C.m33 = A.m33 * B.m33;
    return C;
}

__device__ __forceinline__ void ut_renorm(UT& M) {
    float m1 = fmaxf(fmaxf(M.m00, M.m01), fmaxf(M.m02, M.m03));
    float m2 = fmaxf(fmaxf(M.m11, M.m12), fmaxf(M.m13, M.m22));
    float s = rcp(fmaxf(fmaxf(m1, m2), fmaxf(M.m23, M.m33)));
    M.m00 *= s; M.m01 *= s; M.m02 *= s; M.m03 *= s;
    M.m11 *= s; M.m12 *= s; M.m13 *= s; M.m22 *= s; M.m23 *= s; M.m33 *= s;
}

__device__ __forceinline__ void ut_store11(float* p, const UT& M) {
    p[0] = M.m00; p[1] = M.m01; p[2] = M.m02; p[3] = M.m03;
    p[4] = M.m11; p[5] = M.m12; p[6] = M.m13;
    p[7] = M.m22; p[8] = M.m23; p[9] = M.m33;
}
__device__ __forceinline__ UT ut_load11(const float* p) {
    UT M;
    M.m00 = p[0]; M.m01 = p[1]; M.m02 = p[2]; M.m03 = p[3];
    M.m11 = p[4]; M.m12 = p[5]; M.m13 = p[6];
    M.m22 = p[7]; M.m23 = p[8]; M.m33 = p[9];
    return M;
}

// v' = rescale(v . M)   (row-vec)
__device__ __forceinline__ void vecmat(float& v0, float& v1, float& v2, float& v3,
                                       const float* m) {
    float n0 = v0 * m[0];
    float n1 = fmaf(v0, m[1], v1 * m[4]);
    float n2 = fmaf(v0, m[2], fmaf(v1, m[5], v2 * m[7]));
    float n3 = fmaf(v0, m[3], fmaf(v1, m[6], fmaf(v2, m[8], v3 * m[9])));
    float s = rcp(fmaxf(fmaxf(n0, n1), fmaxf(n2, n3)));
    v0 = n0 * s; v1 = n1 * s; v2 = n2 * s; v3 = n3 * s;
}
// u' = rescale(M . u)   (col-vec)
__device__ __forceinline__ void matvec(const float* m,
                                       float& u0, float& u1, float& u2, float& u3) {
    float n0 = fmaf(m[0], u0, fmaf(m[1], u1, fmaf(m[2], u2, m[3] * u3)));
    float n1 = fmaf(m[4], u1, fmaf(m[5], u2, m[6] * u3));
    float n2 = fmaf(m[7], u2, m[8] * u3);
    float n3 = m[9] * u3;
    float s = rcp(fmaxf(fmaxf(n0, n1), fmaxf(n2, n3)));
    u0 = n0 * s; u1 = n1 * s; u2 = n2 * s; u3 = n3 * s;
}

#define ASTEP(E) do { \
    float4 _e = (E); \
    float n0_ = a0 * A.A00 * _e.x; \
    float n1_ = fmaf(a0, A.A01, a1 * A.A11) * _e.y; \
    float n2_ = fmaf(a0, A.A02, fmaf(a1, A.A12, a2 * A.A22)) * _e.z; \
    float n3_ = fmaf(a1, A.A13, fmaf(a2, A.A23, a3)) * _e.w; \
    float s_ = rcp(fmaxf(fmaxf(n0_, n1_), fmaxf(n2_, n3_))); \
    a0 = n0_ * s_; a1 = n1_ * s_; a2 = n2_ * s_; a3 = n3_ * s_; \
} while (0)

#define BSTEP(E) do { \
    float4 _e = (E); \
    float f0_ = _e.x * b0, f1_ = _e.y * b1, f2_ = _e.z * b2, f3_ = _e.w * b3; \
    float n0_ = fmaf(A.A00, f0_, fmaf(A.A01, f1_, A.A02 * f2_)); \
    float n1_ = fmaf(A.A11, f1_, fmaf(A.A12, f2_, A.A13 * f3_)); \
    float n2_ = fmaf(A.A22, f2_, A.A23 * f3_); \
    float n3_ = f3_; \
    float s_ = rcp(fmaxf(fmaxf(n0_, n1_), fmaxf(n2_, n3_))); \
    b0 = n0_ * s_; b1 = n1_ * s_; b2 = n2_ * s_; b3 = n3_ * s_; \
} while (0)

#define GEMIT(AV, Q) do { \
    float g0_ = (AV).x * b0, g1_ = (AV).y * b1, g2_ = (AV).z * b2, g3_ = (AV).w * b3; \
    float inv_ = rcp(g0_ + g1_ + g2_ + g3_); \
    float q0_ = g0_ * inv_, q1_ = g1_ * inv_, q2_ = g2_ * inv_, q3_ = g3_ * inv_; \
    vals[(Q)*5 + 0] = fmaf(q0_, wv[0][0], fmaf(q1_, wv[1][0], fmaf(q2_, wv[2][0], q3_ * wv[3][0]))); \
    vals[(Q)*5 + 1] = fmaf(q0_, wv[0][1], fmaf(q1_, wv[1][1], fmaf(q2_, wv[2][1], q3_ * wv[3][1]))); \
    vals[(Q)*5 + 2] = fmaf(q0_, wv[0][2], fmaf(q1_, wv[1][2], fmaf(q2_, wv[2][2], q3_ * wv[3][2]))); \
    vals[(Q)*5 + 3] = fmaf(q0_, wv[0][3], fmaf(q1_, wv[1][3], fmaf(q2_, wv[2][3], q3_ * wv[3][3]))); \
    vals[(Q)*5 + 4] = fmaf(q0_, wv[0][4], fmaf(q1_, wv[1][4], fmaf(q2_, wv[2][4], q3_ * wv[3][4]))); \
} while (0)

// le in LDS (LINEAR space): row = t&15 (stride 257 float4), col = t>>4 = chunk id (C=256, L=16)
#define RDLE(T) sle[(((T) & 15) * 257) + ((T) >> 4)]

// op-tree float offsets in uni (stride 11 per op)
#define L0F 0
#define L0B 2816
#define L1F 5632
#define L1B 7040
#define L2F 8448
#define L2B 9152
#define L3F 9856
#define L3B 10208
#define SF  10560
#define SB  10688

__global__ __launch_bounds__(512, 1)
void fused_kernel(const float* __restrict__ x, const float* __restrict__ emit,
                  const float* __restrict__ trans, const float* __restrict__ initl,
                  const float* __restrict__ w, float* __restrict__ out) {
    __shared__ float4 sle[16 * 257];    // 65,792 B
    __shared__ float4 uni[4096];        // 65,536 B: op tree (ph1/2) aliased by alpha/beta (ph3)
    __shared__ float Bmat[SDIM][ADIM];  // 416 B

    float* U = reinterpret_cast<float*>(uni);
    float4* abuf = uni;                 // [k*256 + c], k<8 (phase 3)
    float4* bbuf = uni + 2048;

    const int tid = threadIdx.x;
    const int bidb = blockIdx.x;

    // ---- emission distributions (linear) ----
    if (tid < SDIM) {
        float m = -1e30f;
        #pragma unroll
        for (int a = 0; a < ADIM; ++a) m = fmaxf(m, emit[tid * ADIM + a]);
        float tmp[ADIM];
        float z = 0.f;
        #pragma unroll
        for (int a = 0; a < ADIM; ++a) {
            float e = __expf(emit[tid * ADIM + a] - m);
            tmp[a] = e; z += e;
        }
        float inv = 1.f / z;
        #pragma unroll
        for (int a = 0; a < ADIM; ++a) Bmat[tid][a] = tmp[a] * inv;
    }
    TransA A = make_transA(trans);
    __syncthreads();

    // ---- phase 0: x -> linear e in LDS (rolled; unnormalized dot, constants cancel) ----
    {
        const float4* xbase = reinterpret_cast<const float4*>(x) + (size_t)bidb * 2048 * 13;
        #pragma unroll 1
        for (int i = 0; i < 4; ++i) {
            const float4* xp = xbase + ((size_t)(i * 512 + tid)) * 13;
            float4 buf[13];
            #pragma unroll
            for (int q = 0; q < 13; ++q) buf[q] = xp[q];

            float d00 = 0.f, d01 = 0.f, d02 = 0.f, d03 = 0.f;
            float d10 = 0.f, d11 = 0.f, d12 = 0.f, d13 = 0.f;
            #pragma unroll
            for (int q = 0; q < 13; ++q) {
                float4 u = buf[q];
                #pragma unroll
                for (int j = 0; j < 4; ++j) {
                    const int e = q * 4 + j;
                    float val = (j == 0) ? u.x : (j == 1) ? u.y : (j == 2) ? u.z : u.w;
                    float ev = ex2(val * LOG2E);
                    if (e < ADIM) {
                        d00 = fmaf(ev, Bmat[0][e], d00); d01 = fmaf(ev, Bmat[1][e], d01);
                        d02 = fmaf(ev, Bmat[2][e], d02); d03 = fmaf(ev, Bmat[3][e], d03);
                    } else {
                        const int a = e - ADIM;
                        d10 = fmaf(ev, Bmat[0][a], d10); d11 = fmaf(ev, Bmat[1][a], d11);
                        d12 = fmaf(ev, Bmat[2][a], d12); d13 = fmaf(ev, Bmat[3][a], d13);
                    }
                }
            }
            int t = (i * 512 + tid) << 1;
            RDLE(t) = make_float4(d00, d01, d02, d03);
            RDLE(t + 1) = make_float4(d10, d11, d12, d13);
        }
    }
    __syncthreads();

    const int c = tid & 255;
    const int t0 = c * 16;
    const bool isB = tid >= 256;

    // ---- phase 1: per-(chunk,dir) operator (L=16), rolled ----
    {
        UT M;
        if (!isB) {
            float4 e0 = RDLE(t0);
            if (c == 0) {
                M.m00 = e0.x; M.m11 = e0.y; M.m22 = e0.z; M.m33 = e0.w;
                M.m01 = 0.f; M.m02 = 0.f; M.m03 = 0.f; M.m12 = 0.f; M.m13 = 0.f; M.m23 = 0.f;
            } else {
                M.m00 = A.A00 * e0.x; M.m01 = A.A01 * e0.y; M.m02 = A.A02 * e0.z; M.m03 = 0.f;
                M.m11 = A.A11 * e0.y; M.m12 = A.A12 * e0.z; M.m13 = A.A13 * e0.w;
                M.m22 = A.A22 * e0.z; M.m23 = A.A23 * e0.w; M.m33 = e0.w;
            }
            #pragma unroll 1
            for (int k = 1; k < 16; ++k) fstep(M, A, RDLE(t0 + k));
            ut_renorm(M);
            ut_store11(U + L0F + c * 11, M);
        } else {
            M.m00 = 1.f; M.m11 = 1.f; M.m22 = 1.f; M.m33 = 1.f;
            M.m01 = 0.f; M.m02 = 0.f; M.m03 = 0.f; M.m12 = 0.f; M.m13 = 0.f; M.m23 = 0.f;
            int nst = (c == 255) ? 15 : 16;
            #pragma unroll 1
            for (int k = 0; k < nst; ++k) fstep(M, A, RDLE(t0 + 1 + k));
            ut_renorm(M);
            ut_store11(U + L0B + c * 11, M);
        }
    }
    __syncthreads();

    // ---- phase 2a: L0 pairs -> L1 (128/dir) ----
    if (tid < 256) {
        int dir = tid >> 7;
        int i = tid & 127;
        const float* src = U + (dir ? L0B : L0F);
        float* dst = U + (dir ? L1B : L1F);
        UT P = ut_compose(ut_load11(src + (2 * i) * 11), ut_load11(src + (2 * i + 1) * 11));
        ut_renorm(P);
        ut_store11(dst + i * 11, P);
    }
    __syncthreads();

    // ---- phase 2b: L1 pairs -> L2 (64/dir) ----
    if (tid < 128) {
        int dir = tid >> 6;
        int i = tid & 63;
        const float* src = U + (dir ? L1B : L1F);
        float* dst = U + (dir ? L2B : L2F);
        UT P = ut_compose(ut_load11(src + (2 * i) * 11), ut_load11(src + (2 * i + 1) * 11));
        ut_renorm(P);
        ut_store11(dst + i * 11, P);
    }
    __syncthreads();

    // ---- phase 2c: L2 pairs -> L3 (32/dir) ----
    if (tid < 64) {
        int dir = tid >> 5;
        int i = tid & 31;
        const float* src = U + (dir ? L2B : L2F);
        float* dst = U + (dir ? L3B : L3F);
        UT P = ut_compose(ut_load11(src + (2 * i) * 11), ut_load11(src + (2 * i + 1) * 11));
        ut_renorm(P);
        ut_store11(dst + i * 11, P);
    }
    __syncthreads();

    // ---- phase 2d: two scalar serial scans over 32 L3-ops (rolled) ----
    if (tid == 0) {
        float i0 = initl[0], i1 = initl[1], i2 = initl[2], i3 = initl[3];
        float m = fmaxf(fmaxf(i0, i1), fmaxf(i2, i3));
        float e0 = __expf(i0 - m), e1 = __expf(i1 - m), e2 = __expf(i2 - m), e3 = __expf(i3 - m);
        float s = 1.f / (e0 + e1 + e2 + e3);
        float v0 = e0 * s, v1 = e1 * s, v2 = e2 * s, v3 = e3 * s;
        #pragma unroll 1
        for (int g = 0; g < 32; ++g) {
            U[SF + g * 4 + 0] = v0; U[SF + g * 4 + 1] = v1;
            U[SF + g * 4 + 2] = v2; U[SF + g * 4 + 3] = v3;
            vecmat(v0, v1, v2, v3, U + L3F + g * 11);
        }
    } else if (tid == 64) {
        float u0 = 1.f, u1 = 1.f, u2 = 1.f, u3 = 1.f;
        #pragma unroll 1
        for (int g = 31; g >= 0; --g) {
            U[SB + g * 4 + 0] = u0; U[SB + g * 4 + 1] = u1;
            U[SB + g * 4 + 2] = u2; U[SB + g * 4 + 3] = u3;
            matvec(U + L3B + g * 11, u0, u1, u2, u3);
        }
    }
    __syncthreads();

    // ---- phase 2e: downsweep to per-chunk boundaries (registers) ----
    float fa0, fa1, fa2, fa3;
    float fb0, fb1, fb2, fb3;
    {
        int g = c >> 3;
        if (!isB) {
            fa0 = U[SF + g * 4 + 0]; fa1 = U[SF + g * 4 + 1];
            fa2 = U[SF + g * 4 + 2]; fa3 = U[SF + g * 4 + 3];
            if (c & 4) vecmat(fa0, fa1, fa2, fa3, U + L2F + (2 * g) * 11);
            if (c & 2) vecmat(fa0, fa1, fa2, fa3, U + L1F + ((c >> 2) * 2) * 11);
            if (c & 1) vecmat(fa0, fa1, fa2, fa3, U + L0F + (c - 1) * 11);
        } else {
            fb0 = U[SB + g * 4 + 0]; fb1 = U[SB + g * 4 + 1];
            fb2 = U[SB + g * 4 + 2]; fb3 = U[SB + g * 4 + 3];
            if (!(c & 4)) matvec(U + L2B + (2 * g + 1) * 11, fb0, fb1, fb2, fb3);
            if (!(c & 2)) matvec(U + L1B + ((c >> 2) * 2 + 1) * 11, fb0, fb1, fb2, fb3);
            if (!(c & 1)) matvec(U + L0B + (c + 1) * 11, fb0, fb1, fb2, fb3);
        }
    }
    __syncthreads();   // op-tree reads done; abuf/bbuf may now clobber uni

    // ---- phase 3: replay + gamma.w emit (rolled outer loops) ----
    float wv[SDIM][5];
    #pragma unroll
    for (int s = 0; s < SDIM; ++s)
        #pragma unroll
        for (int o = 0; o < 5; ++o) wv[s][o] = w[s * 5 + o];

    float* opb = out + (size_t)bidb * TDIM * 5;
    float vals[20];

    if (!isB) {
        float a0 = fa0, a1 = fa1, a2 = fa2, a3 = fa3;
        if (c == 0) {
            float4 e = RDLE(0);
            float n0 = a0 * e.x, n1 = a1 * e.y, n2 = a2 * e.z, n3 = a3 * e.w;
            float s = rcp(fmaxf(fmaxf(n0, n1), fmaxf(n2, n3)));
            a0 = n0 * s; a1 = n1 * s; a2 = n2 * s; a3 = n3 * s;
        } else {
            ASTEP(RDLE(t0));
        }
        abuf[0 * 256 + c] = make_float4(a0, a1, a2, a3);
        #pragma unroll 1
        for (int k = 1; k < 8; ++k) {
            ASTEP(RDLE(t0 + k));
            abuf[k * 256 + c] = make_float4(a0, a1, a2, a3);
        }
        __syncthreads();
        float b0, b1, b2, b3;
        #pragma unroll 1
        for (int g2 = 0; g2 < 2; ++g2) {
            #pragma unroll
            for (int q = 0; q < 4; ++q) {
                int k = 8 + g2 * 4 + q;
                ASTEP(RDLE(t0 + k));
                float4 bv = bbuf[(k - 8) * 256 + c];
                b0 = bv.x; b1 = bv.y; b2 = bv.z; b3 = bv.w;
                float4 av = make_float4(a0, a1, a2, a3);
                GEMIT(av, q);
            }
            float4* vo = reinterpret_cast<float4*>(opb + (size_t)(t0 + 8 + g2 * 4) * 5);
            vo[0] = make_float4(vals[0],  vals[1],  vals[2],  vals[3]);
            vo[1] = make_float4(vals[4],  vals[5],  vals[6],  vals[7]);
            vo[2] = make_float4(vals[8],  vals[9],  vals[10], vals[11]);
            vo[3] = make_float4(vals[12], vals[13], vals[14], vals[15]);
            vo[4] = make_float4(vals[16], vals[17], vals[18], vals[19]);
        }
    } else {
        float b0 = fb0, b1 = fb1, b2 = fb2, b3 = fb3;
        bool lastc = (c == 255);
        #pragma unroll 1
        for (int k = 15; k >= 8; --k) {
            if (!(lastc && k == 15)) BSTEP(RDLE(t0 + 1 + k));
            bbuf[(k - 8) * 256 + c] = make_float4(b0, b1, b2, b3);
        }
        __syncthreads();
        #pragma unroll 1
        for (int g2 = 1; g2 >= 0; --g2) {
            #pragma unroll
            for (int q = 3; q >= 0; --q) {
                int k = g2 * 4 + q;
                BSTEP(RDLE(t0 + 1 + k));
                float4 av = abuf[k * 256 + c];
                GEMIT(av, q);
            }
            float4* vo = reinterpret_cast<float4*>(opb + (size_t)(t0 + g2 * 4) * 5);
            vo[0] = make_float4(vals[0],  vals[1],  vals[2],  vals[3]);
            vo[1] = make_float4(vals[4],  vals[5],  vals[6],  vals[7]);
            vo[2] = make_float4(vals[8],  vals[9],  vals[10], vals[11]);
            vo[3] = make_float4(vals[12], vals[13], vals[14], vals[15]);
            vo[4] = make_float4(vals[16], vals[17], vals[18], vals[19]);
        }
    }
}

extern "C" void kernel_launch(void* const* d_in, const int* in_sizes, int n_in,
                              void* d_out, int out_size, void* d_ws, size_t ws_size,
                              hipStream_t stream) {
    const float* x     = (const float*)d_in[0];
    const float* emit  = (const float*)d_in[1];
    const float* trans = (const float*)d_in[2];
    const float* initl = (const float*)d_in[3];
    const float* w     = (const float*)d_in[4];
    float* out = (float*)d_out;

    hipLaunchKernelGGL(fused_kernel, dim3(BDIM), dim3(512), 0, stream,
                       x, emit, trans, initl, w, out);
}

// Round 20
// 39.335 us; speedup vs baseline: 2.8506x; 1.0267x over previous
//
#include <hip/hip_runtime.h>

#define TDIM 4096
#define BDIM 256
#define ADIM 26
#define SDIM 4
#define LOG2E 1.44269504088896340736f

__device__ __forceinline__ float ex2(float x) { return __builtin_amdgcn_exp2f(x); }
__device__ __forceinline__ float rcp(float x) { return __builtin_amdgcn_rcpf(x); }

// Linear-probability transition matrix (masked row softmax), A33 = 1.
struct TransA { float A00, A01, A02, A11, A12, A13, A22, A23, A33; };

__device__ __forceinline__ TransA make_transA(const float* __restrict__ trans) {
    TransA A;
    {
        float l0 = trans[0], l1 = trans[1], l2 = trans[2];
        float m = fmaxf(fmaxf(l0, l1), l2);
        float e0 = __expf(l0 - m), e1 = __expf(l1 - m), e2 = __expf(l2 - m);
        float s = 1.f / (e0 + e1 + e2);
        A.A00 = e0 * s; A.A01 = e1 * s; A.A02 = e2 * s;
    }
    {
        float l1 = trans[5], l2 = trans[6], l3 = trans[7];
        float m = fmaxf(fmaxf(l1, l2), l3);
        float e1 = __expf(l1 - m), e2 = __expf(l2 - m), e3 = __expf(l3 - m);
        float s = 1.f / (e1 + e2 + e3);
        A.A11 = e1 * s; A.A12 = e2 * s; A.A13 = e3 * s;
    }
    {
        float l2 = trans[10], l3 = trans[11];
        float m = fmaxf(l2, l3);
        float e2 = __expf(l2 - m), e3 = __expf(l3 - m);
        float s = 1.f / (e2 + e3);
        A.A22 = e2 * s; A.A23 = e3 * s;
    }
    A.A33 = 1.f;
    return A;
}

struct UT { float m00, m01, m02, m03, m11, m12, m13, m22, m23, m33; };

// M <- rescale( M . (A * diag(e)) )
__device__ __forceinline__ void fstep(UT& M, const TransA& A, float4 e) {
    float n00 = M.m00 * A.A00 * e.x;
    float n01 = fmaf(M.m00, A.A01, M.m01 * A.A11) * e.y;
    float n02 = fmaf(M.m00, A.A02, fmaf(M.m01, A.A12, M.m02 * A.A22)) * e.z;
    float n03 = fmaf(M.m01, A.A13, fmaf(M.m02, A.A23, M.m03)) * e.w;   // A33=1
    float n11 = M.m11 * A.A11 * e.y;
    float n12 = fmaf(M.m11, A.A12, M.m12 * A.A22) * e.z;
    float n13 = fmaf(M.m11, A.A13, fmaf(M.m12, A.A23, M.m13)) * e.w;
    float n22 = M.m22 * A.A22 * e.z;
    float n23 = fmaf(M.m22, A.A23, M.m23) * e.w;
    float n33 = M.m33 * e.w;
    float m1 = fmaxf(fmaxf(n00, n01), fmaxf(n02, n03));
    float m2 = fmaxf(fmaxf(n11, n12), fmaxf(n13, n22));
    float s = rcp(fmaxf(fmaxf(m1, m2), fmaxf(n23, n33)));
    M.m00 = n00 * s; M.m01 = n01 * s; M.m02 = n02 * s; M.m03 = n03 * s;
    M.m11 = n11 * s; M.m12 = n12 * s; M.m13 = n13 * s;
    M.m22 = n22 * s; M.m23 = n23 * s; M.m33 = n33 * s;
}

__device__ __forceinline__ UT ut_compose(const UT& A, const UT& B) {
    UT C;
    C.m00 = A.m00 * B.m00;
    C.m01 = fmaf(A.m00, B.m01, A.m01 * B.m11);
    C.m02 = fmaf(A.m00, B.m02, fmaf(A.m01, B.m12, A.m02 * B.m22));
    C.m03 = fmaf(A.m00, B.m03, fmaf(A.m01, B.m13, fmaf(A.m02, B.m23, A.m03 * B.m33)));
    C.m11 = A.m11 * B.m11;
    C.m12 = fmaf(A.m11, B.m12, A.m12 * B.m22);
    C.m13 = fmaf(A.m11, B.m13, fmaf(A.m12, B.m23, A.m13 * B.m33));
    C.m22 = A.m22 * B.m22;
    C.m23 = fmaf(A.m22, B.m23, A.m23 * B.m33);
    C.m33 = A.m33 * B.m33;
    return C;
}

__device__ __forceinline__ void ut_renorm(UT& M) {
    float m1 = fmaxf(fmaxf(M.m00, M.m01), fmaxf(M.m02, M.m03));
    float m2 = fmaxf(fmaxf(M.m11, M.m12), fmaxf(M.m13, M.m22));
    float s = rcp(fmaxf(fmaxf(m1, m2), fmaxf(M.m23, M.m33)));
    M.m00 *= s; M.m01 *= s; M.m02 *= s; M.m03 *= s;
    M.m11 *= s; M.m12 *= s; M.m13 *= s; M.m22 *= s; M.m23 *= s; M.m33 *= s;
}

__device__ __forceinline__ void ut_store11(float* p, const UT& M) {
    p[0] = M.m00; p[1] = M.m01; p[2] = M.m02; p[3] = M.m03;
    p[4] = M.m11; p[5] = M.m12; p[6] = M.m13;
    p[7] = M.m22; p[8] = M.m23; p[9] = M.m33;
}
__device__ __forceinline__ UT ut_load11(const float* p) {
    UT M;
    M.m00 = p[0]; M.m01 = p[1]; M.m02 = p[2]; M.m03 = p[3];
    M.m11 = p[4]; M.m12 = p[5]; M.m13 = p[6];
    M.m22 = p[7]; M.m23 = p[8]; M.m33 = p[9];
    return M;
}

// v' = rescale(v . M)   (row-vec)
__device__ __forceinline__ void vecmat(float& v0, float& v1, float& v2, float& v3,
                                       const float* m) {
    float n0 = v0 * m[0];
    float n1 = fmaf(v0, m[1], v1 * m[4]);
    float n2 = fmaf(v0, m[2], fmaf(v1, m[5], v2 * m[7]));
    float n3 = fmaf(v0, m[3], fmaf(v1, m[6], fmaf(v2, m[8], v3 * m[9])));
    float s = rcp(fmaxf(fmaxf(n0, n1), fmaxf(n2, n3)));
    v0 = n0 * s; v1 = n1 * s; v2 = n2 * s; v3 = n3 * s;
}
// u' = rescale(M . u)   (col-vec)
__device__ __forceinline__ void matvec(const float* m,
                                       float& u0, float& u1, float& u2, float& u3) {
    float n0 = fmaf(m[0], u0, fmaf(m[1], u1, fmaf(m[2], u2, m[3] * u3)));
    float n1 = fmaf(m[4], u1, fmaf(m[5], u2, m[6] * u3));
    float n2 = fmaf(m[7], u2, m[8] * u3);
    float n3 = m[9] * u3;
    float s = rcp(fmaxf(fmaxf(n0, n1), fmaxf(n2, n3)));
    u0 = n0 * s; u1 = n1 * s; u2 = n2 * s; u3 = n3 * s;
}

#define ASTEP(E) do { \
    float4 _e = (E); \
    float n0_ = a0 * A.A00 * _e.x; \
    float n1_ = fmaf(a0, A.A01, a1 * A.A11) * _e.y; \
    float n2_ = fmaf(a0, A.A02, fmaf(a1, A.A12, a2 * A.A22)) * _e.z; \
    float n3_ = fmaf(a1, A.A13, fmaf(a2, A.A23, a3)) * _e.w; \
    float s_ = rcp(fmaxf(fmaxf(n0_, n1_), fmaxf(n2_, n3_))); \
    a0 = n0_ * s_; a1 = n1_ * s_; a2 = n2_ * s_; a3 = n3_ * s_; \
} while (0)

#define BSTEP(E) do { \
    float4 _e = (E); \
    float f0_ = _e.x * b0, f1_ = _e.y * b1, f2_ = _e.z * b2, f3_ = _e.w * b3; \
    float n0_ = fmaf(A.A00, f0_, fmaf(A.A01, f1_, A.A02 * f2_)); \
    float n1_ = fmaf(A.A11, f1_, fmaf(A.A12, f2_, A.A13 * f3_)); \
    float n2_ = fmaf(A.A22, f2_, A.A23 * f3_); \
    float n3_ = f3_; \
    float s_ = rcp(fmaxf(fmaxf(n0_, n1_), fmaxf(n2_, n3_))); \
    b0 = n0_ * s_; b1 = n1_ * s_; b2 = n2_ * s_; b3 = n3_ * s_; \
} while (0)

#define GEMIT(AV, Q) do { \
    float g0_ = (AV).x * b0, g1_ = (AV).y * b1, g2_ = (AV).z * b2, g3_ = (AV).w * b3; \
    float inv_ = rcp(g0_ + g1_ + g2_ + g3_); \
    float q0_ = g0_ * inv_, q1_ = g1_ * inv_, q2_ = g2_ * inv_, q3_ = g3_ * inv_; \
    vals[(Q)*5 + 0] = fmaf(q0_, wv[0][0], fmaf(q1_, wv[1][0], fmaf(q2_, wv[2][0], q3_ * wv[3][0]))); \
    vals[(Q)*5 + 1] = fmaf(q0_, wv[0][1], fmaf(q1_, wv[1][1], fmaf(q2_, wv[2][1], q3_ * wv[3][1]))); \
    vals[(Q)*5 + 2] = fmaf(q0_, wv[0][2], fmaf(q1_, wv[1][2], fmaf(q2_, wv[2][2], q3_ * wv[3][2]))); \
    vals[(Q)*5 + 3] = fmaf(q0_, wv[0][3], fmaf(q1_, wv[1][3], fmaf(q2_, wv[2][3], q3_ * wv[3][3]))); \
    vals[(Q)*5 + 4] = fmaf(q0_, wv[0][4], fmaf(q1_, wv[1][4], fmaf(q2_, wv[2][4], q3_ * wv[3][4]))); \
} while (0)

// le in LDS (LINEAR): row = t&7 (stride 513 float4), col = t>>3 = chunk id (C=512, L=8)
#define RDLE(T) sle[(((T) & 7) * 513) + ((T) >> 3)]

// op-tree float offsets in uni (stride 11 per op)
#define L0F 0
#define L0B 5632
#define L1F 11264
#define L1B 14080
#define L2F 16896
#define L2B 18304
#define L3F 19712
#define L3B 20416
#define L4F 21120
#define L4B 21472
#define SF  21824
#define SB  21952

__global__ __launch_bounds__(512, 1)
void fused_kernel(const float* __restrict__ x, const float* __restrict__ emit,
                  const float* __restrict__ trans, const float* __restrict__ initl,
                  const float* __restrict__ w, float* __restrict__ out) {
    __shared__ float4 sle[8 * 513];     // 65,664 B
    __shared__ float4 uni[5520];        // 88,320 B: op tree
    __shared__ float Bmat[SDIM][ADIM];  // 416 B

    float* U = reinterpret_cast<float*>(uni);

    const int tid = threadIdx.x;
    const int bidb = blockIdx.x;

    // ---- emission distributions (linear) ----
    if (tid < SDIM) {
        float m = -1e30f;
        #pragma unroll
        for (int a = 0; a < ADIM; ++a) m = fmaxf(m, emit[tid * ADIM + a]);
        float tmp[ADIM];
        float z = 0.f;
        #pragma unroll
        for (int a = 0; a < ADIM; ++a) {
            float e = __expf(emit[tid * ADIM + a] - m);
            tmp[a] = e; z += e;
        }
        float inv = 1.f / z;
        #pragma unroll
        for (int a = 0; a < ADIM; ++a) Bmat[tid][a] = tmp[a] * inv;
    }
    TransA A = make_transA(trans);
    __syncthreads();

    // ---- phase 0: x -> linear e in LDS (rolled) ----
    {
        const float4* xbase = reinterpret_cast<const float4*>(x) + (size_t)bidb * 2048 * 13;
        #pragma unroll 1
        for (int i = 0; i < 4; ++i) {
            const float4* xp = xbase + ((size_t)(i * 512 + tid)) * 13;
            float4 buf[13];
            #pragma unroll
            for (int q = 0; q < 13; ++q) buf[q] = xp[q];

            float d00 = 0.f, d01 = 0.f, d02 = 0.f, d03 = 0.f;
            float d10 = 0.f, d11 = 0.f, d12 = 0.f, d13 = 0.f;
            #pragma unroll
            for (int q = 0; q < 13; ++q) {
                float4 u = buf[q];
                #pragma unroll
                for (int j = 0; j < 4; ++j) {
                    const int e = q * 4 + j;
                    float val = (j == 0) ? u.x : (j == 1) ? u.y : (j == 2) ? u.z : u.w;
                    float ev = ex2(val * LOG2E);
                    if (e < ADIM) {
                        d00 = fmaf(ev, Bmat[0][e], d00); d01 = fmaf(ev, Bmat[1][e], d01);
                        d02 = fmaf(ev, Bmat[2][e], d02); d03 = fmaf(ev, Bmat[3][e], d03);
                    } else {
                        const int a = e - ADIM;
                        d10 = fmaf(ev, Bmat[0][a], d10); d11 = fmaf(ev, Bmat[1][a], d11);
                        d12 = fmaf(ev, Bmat[2][a], d12); d13 = fmaf(ev, Bmat[3][a], d13);
                    }
                }
            }
            int t = (i * 512 + tid) << 1;
            RDLE(t) = make_float4(d00, d01, d02, d03);
            RDLE(t + 1) = make_float4(d10, d11, d12, d13);
        }
    }
    __syncthreads();

    const int c = tid;          // chunk id, C=512, L=8 — each thread owns BOTH dirs
    const int t0 = c * 8;

    // ---- phase 1: fwd + bwd operator per thread, interleaved (ILP-2, shared reads) ----
    {
        UT Mf, Mb;
        float4 e0 = RDLE(t0);
        if (c == 0) {
            Mf.m00 = e0.x; Mf.m11 = e0.y; Mf.m22 = e0.z; Mf.m33 = e0.w;
            Mf.m01 = 0.f; Mf.m02 = 0.f; Mf.m03 = 0.f; Mf.m12 = 0.f; Mf.m13 = 0.f; Mf.m23 = 0.f;
        } else {
            Mf.m00 = A.A00 * e0.x; Mf.m01 = A.A01 * e0.y; Mf.m02 = A.A02 * e0.z; Mf.m03 = 0.f;
            Mf.m11 = A.A11 * e0.y; Mf.m12 = A.A12 * e0.z; Mf.m13 = A.A13 * e0.w;
            Mf.m22 = A.A22 * e0.z; Mf.m23 = A.A23 * e0.w; Mf.m33 = e0.w;
        }
        Mb.m00 = 1.f; Mb.m11 = 1.f; Mb.m22 = 1.f; Mb.m33 = 1.f;
        Mb.m01 = 0.f; Mb.m02 = 0.f; Mb.m03 = 0.f; Mb.m12 = 0.f; Mb.m13 = 0.f; Mb.m23 = 0.f;

        #pragma unroll 1
        for (int k = 1; k < 8; ++k) {
            float4 e = RDLE(t0 + k);
            fstep(Mf, A, e);
            fstep(Mb, A, e);
        }
        if (c < 511) fstep(Mb, A, RDLE(t0 + 8));
        ut_renorm(Mf); ut_renorm(Mb);
        ut_store11(U + L0F + c * 11, Mf);
        ut_store11(U + L0B + c * 11, Mb);
    }
    __syncthreads();

    // ---- phase 2a: L0 pairs -> L1 (256/dir), 512 threads ----
    {
        int dir = tid >> 8, i = tid & 255;
        const float* src = U + (dir ? L0B : L0F);
        float* dst = U + (dir ? L1B : L1F);
        UT P = ut_compose(ut_load11(src + (2 * i) * 11), ut_load11(src + (2 * i + 1) * 11));
        ut_renorm(P);
        ut_store11(dst + i * 11, P);
    }
    __syncthreads();

    // ---- phase 2b: L1 -> L2 (128/dir) ----
    if (tid < 256) {
        int dir = tid >> 7, i = tid & 127;
        const float* src = U + (dir ? L1B : L1F);
        float* dst = U + (dir ? L2B : L2F);
        UT P = ut_compose(ut_load11(src + (2 * i) * 11), ut_load11(src + (2 * i + 1) * 11));
        ut_renorm(P);
        ut_store11(dst + i * 11, P);
    }
    __syncthreads();

    // ---- phase 2c: L2 -> L3 (64/dir) ----
    if (tid < 128) {
        int dir = tid >> 6, i = tid & 63;
        const float* src = U + (dir ? L2B : L2F);
        float* dst = U + (dir ? L3B : L3F);
        UT P = ut_compose(ut_load11(src + (2 * i) * 11), ut_load11(src + (2 * i + 1) * 11));
        ut_renorm(P);
        ut_store11(dst + i * 11, P);
    }
    __syncthreads();

    // ---- phase 2d: L3 -> L4 (32/dir) ----
    if (tid < 64) {
        int dir = tid >> 5, i = tid & 31;
        const float* src = U + (dir ? L3B : L3F);
        float* dst = U + (dir ? L4B : L4F);
        UT P = ut_compose(ut_load11(src + (2 * i) * 11), ut_load11(src + (2 * i + 1) * 11));
        ut_renorm(P);
        ut_store11(dst + i * 11, P);
    }
    __syncthreads();

    // ---- phase 2e: two scalar serial scans over 32 L4-ops (rolled) ----
    if (tid == 0) {
        float i0 = initl[0], i1 = initl[1], i2 = initl[2], i3 = initl[3];
        float m = fmaxf(fmaxf(i0, i1), fmaxf(i2, i3));
        float e0 = __expf(i0 - m), e1 = __expf(i1 - m), e2 = __expf(i2 - m), e3 = __expf(i3 - m);
        float s = 1.f / (e0 + e1 + e2 + e3);
        float v0 = e0 * s, v1 = e1 * s, v2 = e2 * s, v3 = e3 * s;
        #pragma unroll 1
        for (int g = 0; g < 32; ++g) {
            U[SF + g * 4 + 0] = v0; U[SF + g * 4 + 1] = v1;
            U[SF + g * 4 + 2] = v2; U[SF + g * 4 + 3] = v3;
            vecmat(v0, v1, v2, v3, U + L4F + g * 11);
        }
    } else if (tid == 64) {
        float u0 = 1.f, u1 = 1.f, u2 = 1.f, u3 = 1.f;
        #pragma unroll 1
        for (int g = 31; g >= 0; --g) {
            U[SB + g * 4 + 0] = u0; U[SB + g * 4 + 1] = u1;
            U[SB + g * 4 + 2] = u2; U[SB + g * 4 + 3] = u3;
            matvec(U + L4B + g * 11, u0, u1, u2, u3);
        }
    }
    __syncthreads();

    // ---- phase 2f: downsweep, both boundaries per thread (registers) ----
    float fa0, fa1, fa2, fa3;
    float fb0, fb1, fb2, fb3;
    {
        int g = c >> 4;
        fa0 = U[SF + g * 4 + 0]; fa1 = U[SF + g * 4 + 1];
        fa2 = U[SF + g * 4 + 2]; fa3 = U[SF + g * 4 + 3];
        if (c & 8) vecmat(fa0, fa1, fa2, fa3, U + L3F + (2 * g) * 11);
        if (c & 4) vecmat(fa0, fa1, fa2, fa3, U + L2F + ((c >> 3) * 2) * 11);
        if (c & 2) vecmat(fa0, fa1, fa2, fa3, U + L1F + ((c >> 2) * 2) * 11);
        if (c & 1) vecmat(fa0, fa1, fa2, fa3, U + L0F + (c - 1) * 11);

        fb0 = U[SB + g * 4 + 0]; fb1 = U[SB + g * 4 + 1];
        fb2 = U[SB + g * 4 + 2]; fb3 = U[SB + g * 4 + 3];
        if (!(c & 8)) matvec(U + L3B + (2 * g + 1) * 11, fb0, fb1, fb2, fb3);
        if (!(c & 4)) matvec(U + L2B + ((c >> 3) * 2 + 1) * 11, fb0, fb1, fb2, fb3);
        if (!(c & 2)) matvec(U + L1B + ((c >> 2) * 2 + 1) * 11, fb0, fb1, fb2, fb3);
        if (!(c & 1)) matvec(U + L0B + (c + 1) * 11, fb0, fb1, fb2, fb3);
    }

    // ---- phase 3: per-thread beta + alpha replay + emit (fully unrolled, static idx) ----
    float wv[SDIM][5];
    #pragma unroll
    for (int s = 0; s < SDIM; ++s)
        #pragma unroll
        for (int o = 0; o < 5; ++o) wv[s][o] = w[s * 5 + o];

    float* opb = out + (size_t)bidb * TDIM * 5;

    float4 br[8];
    {
        float b0 = fb0, b1 = fb1, b2 = fb2, b3 = fb3;
        #pragma unroll
        for (int k = 7; k >= 0; --k) {
            if (!(c == 511 && k == 7)) BSTEP(RDLE(t0 + 1 + k));
            br[k] = make_float4(b0, b1, b2, b3);
        }
    }
    float4 ar[8];
    {
        float a0 = fa0, a1 = fa1, a2 = fa2, a3 = fa3;
        #pragma unroll
        for (int k = 0; k < 8; ++k) {
            if (c == 0 && k == 0) {
                float4 e = RDLE(0);
                float n0 = a0 * e.x, n1 = a1 * e.y, n2 = a2 * e.z, n3 = a3 * e.w;
                float s = rcp(fmaxf(fmaxf(n0, n1), fmaxf(n2, n3)));
                a0 = n0 * s; a1 = n1 * s; a2 = n2 * s; a3 = n3 * s;
            } else {
                ASTEP(RDLE(t0 + k));
            }
            ar[k] = make_float4(a0, a1, a2, a3);
        }
    }
    {
        float vals[20];
        float b0, b1, b2, b3;
        #pragma unroll
        for (int g2 = 0; g2 < 2; ++g2) {
            #pragma unroll
            for (int q = 0; q < 4; ++q) {
                int k = g2 * 4 + q;
                b0 = br[k].x; b1 = br[k].y; b2 = br[k].z; b3 = br[k].w;
                GEMIT(ar[k], q);
            }
            float4* vo = reinterpret_cast<float4*>(opb + (size_t)(t0 + g2 * 4) * 5);
            vo[0] = make_float4(vals[0],  vals[1],  vals[2],  vals[3]);
            vo[1] = make_float4(vals[4],  vals[5],  vals[6],  vals[7]);
            vo[2] = make_float4(vals[8],  vals[9],  vals[10], vals[11]);
            vo[3] = make_float4(vals[12], vals[13], vals[14], vals[15]);
            vo[4] = make_float4(vals[16], vals[17], vals[18], vals[19]);
        }
    }
}

extern "C" void kernel_launch(void* const* d_in, const int* in_sizes, int n_in,
                              void* d_out, int out_size, void* d_ws, size_t ws_size,
                              hipStream_t stream) {
    const float* x     = (const float*)d_in[0];
    const float* emit  = (const float*)d_in[1];
    const float* trans = (const float*)d_in[2];
    const float* initl = (const float*)d_in[3];
    const float* w     = (const float*)d_in[4];
    float* out = (float*)d_out;

    hipLaunchKernelGGL(fused_kernel, dim3(BDIM), dim3(512), 0, stream,
                       x, emit, trans, initl, w, out);
}